// Round 3
// baseline (1664.066 us; speedup 1.0000x reference)
//
#include <hip/hip_runtime.h>

#define NB 512
#define T 128
#define NS 32
#define NC 16
#define NSC 48
#define PF 52   // pad stride for sF, sW, sQt (208 B rows, 16B-aligned)
#define PV 36   // pad stride for sV (144 B rows, 16B-aligned)
#define PK 36   // pad stride for sKt

__device__ __forceinline__ float4 ld4(const float* p) { return *(const float4*)p; }
__device__ __forceinline__ void st4(float* p, float4 v) { *(float4*)p = v; }
__device__ __forceinline__ void fma4(float4& a, float s, float4 f) {
    a.x = fmaf(s, f.x, a.x); a.y = fmaf(s, f.y, a.y);
    a.z = fmaf(s, f.z, a.z); a.w = fmaf(s, f.w, a.w);
}
__device__ __forceinline__ float dot4(float4 a, float4 b) {
    return fmaf(a.x, b.x, fmaf(a.y, b.y, fmaf(a.z, b.z, a.w * b.w)));
}
__device__ __forceinline__ float rlane(float v, int l) {
    return __uint_as_float(__builtin_amdgcn_readlane(__float_as_uint(v), l));
}

// ================= backward Riccati kernel =================
// R2: 4x4 tiles everywhere (2x ds_read_b128 per 16 fma, was b64+b128 per 8),
// wave-aligned roles:
//  A: w0 + w1.lo = W=V@F tiles (96x 4x4); w2.lo = z, w2 = B-prefetch;
//     w3 = C-prefetch (Qxx Qg) + p-prefetch
//  B: w2(<48) = Quu|Qux tiles; w3(<48) = qt
//  C: w0 = Gauss-Jordan; w3 = Qxx tiles
//  D: w1 = V=Qxx+Qxu@K tiles; w2 = v + k->ws; w3 = K->ws
__global__ __launch_bounds__(256, 2)
void lqr_backward(const float* __restrict__ Q,
                  const float* __restrict__ p,
                  const float* __restrict__ A,
                  const float* __restrict__ Bm,
                  const float* __restrict__ c1,
                  float* __restrict__ Kws,
                  float* __restrict__ kws)
{
    const int b = blockIdx.x;
    const int tid = threadIdx.x;
    const int lane = tid & 63;
    const int wv = tid >> 6;

    __shared__ __align__(16) float sF[NS][PF];
    __shared__ __align__(16) float sW[NS][PF];
    __shared__ __align__(16) float sQt[NSC][PF];
    __shared__ __align__(16) float sV[NS][PV];
    __shared__ __align__(16) float sKt[NC][PK];
    __shared__ __align__(16) float sz[NS];
    __shared__ __align__(16) float sqt[NSC];
    __shared__ __align__(16) float sv[NS];
    __shared__ __align__(16) float sc1[NS];
    __shared__ __align__(16) float skt[NC];

    for (int e = tid; e < NS * NSC; e += 256) {
        int i = e / NSC, j = e % NSC;
        sF[i][j] = (j < NS) ? A[(size_t)b * NS * NS + i * NS + j]
                            : Bm[(size_t)b * NS * NC + i * NC + (j - NS)];
    }
    for (int e = tid; e < NS * NS; e += 256) sV[e >> 5][e & 31] = 0.f;
    if (tid < NS) { sv[tid] = 0.f; sc1[tid] = c1[(size_t)b * NS + tid]; }
    __syncthreads();

    for (int t = T - 1; t >= 0; --t) {
        const float* Qg = Q + ((size_t)b * T + t) * NSC * NSC;

        // ---------------- Phase A ----------------
        float4 qb0 = {0,0,0,0}, qb1 = {0,0,0,0}, qb2 = {0,0,0,0}, qb3 = {0,0,0,0};
        float4 qc0 = {0,0,0,0}, qc1 = {0,0,0,0}, qc2 = {0,0,0,0}, qc3 = {0,0,0,0};
        float preg = 0.f;
        int i0b = 0, j0b = 0, i0c = 0, j0c = 0;

        if (wv == 2) {
            if (lane < 48) {   // prefetch Qg rows 32..47 for phase B tiles
                i0b = NS + (lane / 12) * 4; j0b = (lane % 12) * 4;
                qb0 = ld4(Qg + (i0b + 0) * NSC + j0b);
                qb1 = ld4(Qg + (i0b + 1) * NSC + j0b);
                qb2 = ld4(Qg + (i0b + 2) * NSC + j0b);
                qb3 = ld4(Qg + (i0b + 3) * NSC + j0b);
            }
            if (lane < 32) {   // z = v + V @ c1
                float a = sv[lane];
                #pragma unroll
                for (int k0 = 0; k0 < NS; k0 += 4)
                    a += dot4(ld4(&sV[lane][k0]), ld4(&sc1[k0]));
                sz[lane] = a;
            }
        } else if (wv == 3) {  // prefetch Qxx Qg block for phase C + p
            i0c = (lane >> 3) * 4; j0c = (lane & 7) * 4;
            qc0 = ld4(Qg + (i0c + 0) * NSC + j0c);
            qc1 = ld4(Qg + (i0c + 1) * NSC + j0c);
            qc2 = ld4(Qg + (i0c + 2) * NSC + j0c);
            qc3 = ld4(Qg + (i0c + 3) * NSC + j0c);
            if (lane < 48) preg = p[((size_t)b * T + t) * NSC + lane];
        }
        if (tid < 96) {        // W = V @ F, 4x4 tiles
            const int i0 = (tid / 12) * 4, j0 = (tid % 12) * 4;
            float4 a0 = {0,0,0,0}, a1 = {0,0,0,0}, a2 = {0,0,0,0}, a3 = {0,0,0,0};
            #pragma unroll 8
            for (int k = 0; k < NS; ++k) {
                float4 v4 = ld4(&sV[k][i0]);   // V symmetric
                float4 f4 = ld4(&sF[k][j0]);
                fma4(a0, v4.x, f4); fma4(a1, v4.y, f4);
                fma4(a2, v4.z, f4); fma4(a3, v4.w, f4);
            }
            st4(&sW[i0 + 0][j0], a0); st4(&sW[i0 + 1][j0], a1);
            st4(&sW[i0 + 2][j0], a2); st4(&sW[i0 + 3][j0], a3);
        }
        __syncthreads();

        // ---------------- Phase B ----------------
        if (wv == 2 && lane < 48) {   // Qt rows 32..47 = Qg + F^T W
            float4 a0 = qb0, a1 = qb1, a2 = qb2, a3 = qb3;
            #pragma unroll 8
            for (int k = 0; k < NS; ++k) {
                float4 f4 = ld4(&sF[k][i0b]);   // F[k][i0b..i0b+3]
                float4 w4 = ld4(&sW[k][j0b]);
                fma4(a0, f4.x, w4); fma4(a1, f4.y, w4);
                fma4(a2, f4.z, w4); fma4(a3, f4.w, w4);
            }
            st4(&sQt[i0b + 0][j0b], a0); st4(&sQt[i0b + 1][j0b], a1);
            st4(&sQt[i0b + 2][j0b], a2); st4(&sQt[i0b + 3][j0b], a3);
        } else if (wv == 3 && lane < 48) {   // qt = p + F^T z
            float a = preg;
            #pragma unroll 8
            for (int k = 0; k < NS; ++k) a = fmaf(sF[k][lane], sz[k], a);
            sqt[lane] = a;
        }
        __syncthreads();

        // ---------------- Phase C ----------------
        if (wv == 0) {   // Gauss-Jordan inverse of Quu applied to [Qux|qu]
            float R[NC];
            if (lane < NC) {
                #pragma unroll
                for (int i = 0; i < NC; ++i) R[i] = sQt[NS + i][NS + lane];
            } else if (lane < NSC) {
                #pragma unroll
                for (int i = 0; i < NC; ++i) R[i] = sQt[NS + i][lane - NC];
            } else if (lane == NSC) {
                #pragma unroll
                for (int i = 0; i < NC; ++i) R[i] = sqt[NS + i];
            } else {
                #pragma unroll
                for (int i = 0; i < NC; ++i) R[i] = 0.f;
            }
            #pragma unroll
            for (int k = 0; k < NC; ++k) {
                float pk = rlane(R[k], k);
                float inv = __builtin_amdgcn_rcpf(pk);
                inv = inv * fmaf(-pk, inv, 2.0f);
                float tm = R[k] * inv;
                #pragma unroll
                for (int i = 0; i < NC; ++i) {
                    if (i == k) continue;
                    float cki = rlane(R[i], k);
                    R[i] = fmaf(-tm, cki, R[i]);
                }
                R[k] = tm;
            }
            if (lane >= NC && lane < NSC) {
                const int c = lane - NC;
                #pragma unroll
                for (int i = 0; i < NC; ++i) sKt[i][c] = -R[i];
            } else if (lane == NSC) {
                #pragma unroll
                for (int i = 0; i < NC; ++i) skt[i] = -R[i];
            }
        } else if (wv == 3) {   // Qxx = Qg + F^T W (rows 0..31, cols 0..31)
            float4 a0 = qc0, a1 = qc1, a2 = qc2, a3 = qc3;
            #pragma unroll 8
            for (int k = 0; k < NS; ++k) {
                float4 f4 = ld4(&sF[k][i0c]);
                float4 w4 = ld4(&sW[k][j0c]);
                fma4(a0, f4.x, w4); fma4(a1, f4.y, w4);
                fma4(a2, f4.z, w4); fma4(a3, f4.w, w4);
            }
            st4(&sQt[i0c + 0][j0c], a0); st4(&sQt[i0c + 1][j0c], a1);
            st4(&sQt[i0c + 2][j0c], a2); st4(&sQt[i0c + 3][j0c], a3);
        }
        __syncthreads();

        // ---------------- Phase D ----------------
        if (wv == 1) {   // V = Qxx + Qxu @ K, 4x4 tiles (64 lanes = 64 tiles)
            const int i0 = (lane >> 3) * 4, j0 = (lane & 7) * 4;
            float4 a0 = ld4(&sQt[i0 + 0][j0]), a1 = ld4(&sQt[i0 + 1][j0]);
            float4 a2 = ld4(&sQt[i0 + 2][j0]), a3 = ld4(&sQt[i0 + 3][j0]);
            #pragma unroll
            for (int k = 0; k < NC; ++k) {
                float4 q4 = ld4(&sQt[NS + k][i0]);   // Qxu[i0..i0+3][k] = Qux[k][i0..]
                float4 k4 = ld4(&sKt[k][j0]);
                fma4(a0, q4.x, k4); fma4(a1, q4.y, k4);
                fma4(a2, q4.z, k4); fma4(a3, q4.w, k4);
            }
            st4(&sV[i0 + 0][j0], a0); st4(&sV[i0 + 1][j0], a1);
            st4(&sV[i0 + 2][j0], a2); st4(&sV[i0 + 3][j0], a3);
        } else if (wv == 2) {
            if (lane < 32) {      // v = qx + Qxu @ kt
                float a = sqt[lane];
                #pragma unroll
                for (int k = 0; k < NC; ++k) a = fmaf(sQt[NS + k][lane], skt[k], a);
                sv[lane] = a;
            } else if (lane < 48) {
                kws[((size_t)b * T + t) * NC + (lane - 32)] = skt[lane - 32];
            }
        } else if (wv == 3) {     // K -> workspace
            float4* Kg4 = (float4*)(Kws + ((size_t)b * T + t) * NC * NS);
            int e = lane * 2;
            Kg4[e]     = ld4(&sKt[e >> 3][(e & 7) * 4]);
            Kg4[e + 1] = ld4(&sKt[(e + 1) >> 3][((e + 1) & 7) * 4]);
        }
        __syncthreads();
    }
}

// ================= forward chain kernel =================
// wave0: serial x/u chain via readlane; waves1-3: stage next K chunk and
// write x,u outputs for previous chunk. Cost moved to a separate kernel.
__global__ __launch_bounds__(256, 2)
void lqr_chain(const float* __restrict__ x_init,
               const float* __restrict__ A,
               const float* __restrict__ Bm,
               const float* __restrict__ c1,
               const float* __restrict__ Kws,
               const float* __restrict__ kws,
               float* __restrict__ out_x,
               float* __restrict__ out_u)
{
    const int b = blockIdx.x;
    const int tid = threadIdx.x;
    const int lane = tid & 63;
    const int wv = tid >> 6;

    __shared__ __align__(16) float sK[2][8 * 576];
    __shared__ __align__(16) float sk[2][128];
    __shared__ __align__(16) float sxu[2][8][48];

    float4 Freg[12];
    float c1reg = 0.f, xu = 0.f;

    if (wv == 0) {
        const int i = lane & 31;
        const float* Ar = A + (size_t)b * NS * NS + i * NS;
        const float* Br = Bm + (size_t)b * NS * NC + i * NC;
        #pragma unroll
        for (int g = 0; g < 8; ++g) Freg[g] = ld4(Ar + g * 4);
        #pragma unroll
        for (int g = 0; g < 4; ++g) Freg[8 + g] = ld4(Br + g * 4);
        c1reg = c1[(size_t)b * NS + i];
        xu = x_init[(size_t)b * NS + i];
    } else {
        const float4* src = (const float4*)(Kws + (size_t)b * T * NC * NS);
        int ct = tid - 64;
        for (int idx = ct; idx < 1024; idx += 192) {
            int s = idx >> 7, rem = idx & 127, row = rem >> 3, jg = rem & 7;
            st4(&sK[0][s * 576 + row * 36 + jg * 4], src[idx]);
        }
        if (ct < 32) st4(&sk[0][ct * 4], ((const float4*)(kws + (size_t)b * T * NC))[ct]);
    }
    __syncthreads();

    for (int it = 0; it <= 16; ++it) {
        if (wv == 0) {
            if (it < 16) {
                const int buf = it & 1;
                for (int s = 0; s < 8; ++s) {
                    const float* kb = &sK[buf][s * 576 + (lane & 15) * 36];
                    float4 Kq[8];
                    #pragma unroll
                    for (int g = 0; g < 8; ++g) Kq[g] = ld4(kb + g * 4);
                    float ktv = sk[buf][s * 16 + (lane & 15)];

                    float u0 = 0.f, u1 = 0.f;
                    #pragma unroll
                    for (int g = 0; g < 8; ++g) {
                        float x0 = rlane(xu, 4 * g + 0);
                        float x1 = rlane(xu, 4 * g + 1);
                        float x2 = rlane(xu, 4 * g + 2);
                        float x3 = rlane(xu, 4 * g + 3);
                        u0 = fmaf(Kq[g].x, x0, u0); u1 = fmaf(Kq[g].y, x1, u1);
                        u0 = fmaf(Kq[g].z, x2, u0); u1 = fmaf(Kq[g].w, x3, u1);
                    }
                    if (lane >= NS && lane < NSC) xu = u0 + u1 + ktv;
                    if (lane < NSC) sxu[buf][s][lane] = xu;

                    float a0 = 0.f, a1 = 0.f;
                    #pragma unroll
                    for (int g = 0; g < 12; ++g) {
                        float x0 = rlane(xu, 4 * g + 0);
                        float x1 = rlane(xu, 4 * g + 1);
                        float x2 = rlane(xu, 4 * g + 2);
                        float x3 = rlane(xu, 4 * g + 3);
                        a0 = fmaf(Freg[g].x, x0, a0); a1 = fmaf(Freg[g].y, x1, a1);
                        a0 = fmaf(Freg[g].z, x2, a0); a1 = fmaf(Freg[g].w, x3, a1);
                    }
                    if (lane < NS) xu = a0 + a1 + c1reg;
                }
            }
        } else {
            const int ct = tid - 64;
            if (it < 15) {
                const int nbuf = (it + 1) & 1;
                const float4* src = (const float4*)(Kws + ((size_t)b * T + (it + 1) * 8) * NC * NS);
                for (int idx = ct; idx < 1024; idx += 192) {
                    int s = idx >> 7, rem = idx & 127, row = rem >> 3, jg = rem & 7;
                    st4(&sK[nbuf][s * 576 + row * 36 + jg * 4], src[idx]);
                }
                if (ct < 32) st4(&sk[nbuf][ct * 4],
                                 ((const float4*)(kws + ((size_t)b * T + (it + 1) * 8) * NC))[ct]);
            }
            if (it >= 1 && ct < 96) {   // write x,u of chunk it-1
                const int buf = (it - 1) & 1;
                const int s = ct / 12, rr = ct % 12;
                const int t = (it - 1) * 8 + s;
                if (rr < 8)
                    st4(out_x + ((size_t)b * T + t) * NS + rr * 4,
                        ld4(&sxu[buf][s][rr * 4]));
                else
                    st4(out_u + ((size_t)b * T + t) * NC + (rr - 8) * 4,
                        ld4(&sxu[buf][s][32 + (rr - 8) * 4]));
            }
        }
        __syncthreads();
    }
}

// ================= cost kernel =================
// One block per batch element; xu staged in LDS; Q read as a pure
// coalesced float4 stream. HBM-bound by design.
__global__ __launch_bounds__(256, 2)
void lqr_cost(const float* __restrict__ Q,
              const float* __restrict__ p,
              const float* __restrict__ out_x,
              const float* __restrict__ out_u,
              float* __restrict__ out_cost)
{
    const int b = blockIdx.x;
    const int tid = threadIdx.x;

    __shared__ __align__(16) float sxu[T][NSC];   // 24 KB
    __shared__ float sred[4];

    const float4* gx = (const float4*)(out_x + (size_t)b * T * NS);   // 1024 f4
    const float4* gu = (const float4*)(out_u + (size_t)b * T * NC);   // 512 f4
    for (int q = tid; q < 1024; q += 256) {
        int t = q >> 3, r = q & 7;
        st4(&sxu[t][r * 4], gx[q]);
    }
    for (int q = tid; q < 512; q += 256) {
        int t = q >> 2, r = q & 3;
        st4(&sxu[t][NS + r * 4], gu[q]);
    }
    __syncthreads();

    float acc = 0.f;
    const float4* Qf4 = (const float4*)(Q + (size_t)b * T * NSC * NSC);
    for (int q = tid; q < T * 576; q += 256) {
        int t = q / 576, rem = q % 576;
        int i = rem / 12, jg = rem % 12;
        float4 qv = Qf4[q];
        float4 xv = ld4(&sxu[t][jg * 4]);
        acc = fmaf(0.5f * sxu[t][i], dot4(qv, xv), acc);
    }
    const float* pg = p + (size_t)b * T * NSC;
    for (int e = tid; e < T * NSC; e += 256) {
        int t = e / NSC, j = e % NSC;
        acc = fmaf(pg[e], sxu[t][j], acc);
    }

    for (int off = 32; off > 0; off >>= 1)
        acc += __shfl_down(acc, off, 64);
    if ((tid & 63) == 0) sred[tid >> 6] = acc;
    __syncthreads();
    if (tid == 0) out_cost[b] = (sred[0] + sred[1]) + (sred[2] + sred[3]);
}

extern "C" void kernel_launch(void* const* d_in, const int* in_sizes, int n_in,
                              void* d_out, int out_size, void* d_ws, size_t ws_size,
                              hipStream_t stream) {
    const float* x_init = (const float*)d_in[0];
    const float* Q      = (const float*)d_in[1];
    const float* p      = (const float*)d_in[2];
    const float* A      = (const float*)d_in[3];
    const float* Bm     = (const float*)d_in[4];
    const float* c1     = (const float*)d_in[5];

    float* out      = (float*)d_out;
    float* out_x    = out;
    float* out_u    = out + (size_t)NB * T * NS;
    float* out_cost = out + (size_t)NB * T * (NS + NC);

    float* Kws = (float*)d_ws;
    float* kws = Kws + (size_t)NB * T * NC * NS;

    lqr_backward<<<NB, 256, 0, stream>>>(Q, p, A, Bm, c1, Kws, kws);
    lqr_chain<<<NB, 256, 0, stream>>>(x_init, A, Bm, c1, Kws, kws, out_x, out_u);
    lqr_cost<<<NB, 256, 0, stream>>>(Q, p, out_x, out_u, out_cost);
}

// Round 4
// 1552.090 us; speedup vs baseline: 1.0721x; 1.0721x over previous
//
#include <hip/hip_runtime.h>

#define NB 512
#define T 128
#define NS 32
#define NC 16
#define NSC 48
#define PF 52   // pad stride for sF, sW, sQt
#define PV 36   // pad stride for sV
#define PK 36   // pad stride for sKt

__device__ __forceinline__ float4 ld4(const float* p) { return *(const float4*)p; }
__device__ __forceinline__ void st4(float* p, float4 v) { *(float4*)p = v; }
__device__ __forceinline__ void fma4(float4& a, float s, float4 f) {
    a.x = fmaf(s, f.x, a.x); a.y = fmaf(s, f.y, a.y);
    a.z = fmaf(s, f.z, a.z); a.w = fmaf(s, f.w, a.w);
}
__device__ __forceinline__ float dot4(float4 a, float4 b) {
    return fmaf(a.x, b.x, fmaf(a.y, b.y, fmaf(a.z, b.z, a.w * b.w)));
}
__device__ __forceinline__ float rlane(float v, int l) {
    return __uint_as_float(__builtin_amdgcn_readlane(__float_as_uint(v), l));
}

// ================= backward Riccati kernel =================
// R3: latency-bound regime -> maximize thread parallelism per phase.
//  A: W=V@F (192 thr, 2x4 tiles) ; z (32 thr)
//  B: ALL of Qt in one phase: Qux/Quu (96 thr) + Qxx (128 thr) + qt (32 thr),
//     consuming Q/p prefetched a FULL STEP ahead (registers)
//  C: wave0 Gauss-Jordan ; tid>=64 prefetch next step's Q/p fragments
//  D: V=Qxx+Qxu@K (128 thr) + v (32) + K,k->ws (32) ; wave0 prefetches its frag
__global__ __launch_bounds__(256, 2)
void lqr_backward(const float* __restrict__ Q,
                  const float* __restrict__ p,
                  const float* __restrict__ A,
                  const float* __restrict__ Bm,
                  const float* __restrict__ c1,
                  float* __restrict__ Kws,
                  float* __restrict__ kws)
{
    const int b = blockIdx.x;
    const int tid = threadIdx.x;
    const int lane = tid & 63;
    const int wv = tid >> 6;

    __shared__ __align__(16) float sF[NS][PF];
    __shared__ __align__(16) float sW[NS][PF];
    __shared__ __align__(16) float sQt[NSC][PF];
    __shared__ __align__(16) float sV[NS][PV];
    __shared__ __align__(16) float sKt[NC][PK];
    __shared__ __align__(16) float sz[NS];
    __shared__ __align__(16) float sqt[NSC];
    __shared__ __align__(16) float sv[NS];
    __shared__ __align__(16) float sc1[NS];
    __shared__ __align__(16) float skt[NC];

    for (int e = tid; e < NS * NSC; e += 256) {
        int i = e / NSC, j = e % NSC;
        sF[i][j] = (j < NS) ? A[(size_t)b * NS * NS + i * NS + j]
                            : Bm[(size_t)b * NS * NC + i * NC + (j - NS)];
    }
    for (int e = tid; e < NS * NS; e += 256) sV[e >> 5][e & 31] = 0.f;
    if (tid < NS) { sv[tid] = 0.f; sc1[tid] = c1[(size_t)b * NS + tid]; }

    // ---- B-phase role constants ----
    const int i0b = NS + (tid / 12) * 2, j0b = (tid % 12) * 4;   // tid < 96 (Qux/Quu)
    const int ctx = tid - 96;
    const int i0x = (ctx >> 3) * 2, j0x = (ctx & 7) * 4;         // 96..223 (Qxx / V)
    const int ctq = tid - 224;                                   // 224..255 (qt / v)

    // prefetched Q/p fragments for the NEXT step to be processed
    float4 pf0 = {0,0,0,0}, pf1 = {0,0,0,0};
    float pp0 = 0.f, pp1 = 0.f;

    #define PREFETCH(tt) do {                                                   \
        const float* Qn = Q + ((size_t)b * T + (tt)) * NSC * NSC;               \
        if (tid < 96) {                                                         \
            pf0 = ld4(Qn + i0b * NSC + j0b);                                    \
            pf1 = ld4(Qn + (i0b + 1) * NSC + j0b);                              \
        } else if (tid < 224) {                                                 \
            pf0 = ld4(Qn + i0x * NSC + j0x);                                    \
            pf1 = ld4(Qn + (i0x + 1) * NSC + j0x);                              \
        } else {                                                                \
            pp0 = p[((size_t)b * T + (tt)) * NSC + ctq];                        \
            if (ctq < 16) pp1 = p[((size_t)b * T + (tt)) * NSC + 32 + ctq];     \
        }                                                                       \
    } while (0)

    PREFETCH(T - 1);
    __syncthreads();

    for (int t = T - 1; t >= 0; --t) {
        // ---------------- Phase A: W = V@F ; z ----------------
        if (tid < 192) {
            const int i0 = (tid / 12) * 2, j0 = (tid % 12) * 4;
            float4 a0 = {0,0,0,0}, a1 = {0,0,0,0};
            #pragma unroll 8
            for (int k = 0; k < NS; ++k) {
                float2 v2 = *(const float2*)&sV[k][i0];   // V symmetric
                float4 f4 = ld4(&sF[k][j0]);
                fma4(a0, v2.x, f4); fma4(a1, v2.y, f4);
            }
            st4(&sW[i0][j0], a0); st4(&sW[i0 + 1][j0], a1);
        } else if (tid < 224) {
            int i = tid - 192;
            float a = sv[i];
            #pragma unroll
            for (int k0 = 0; k0 < NS; k0 += 4)
                a += dot4(ld4(&sV[i][k0]), ld4(&sc1[k0]));
            sz[i] = a;
        }
        __syncthreads();

        // ---------------- Phase B: full Qt + qt (consume prefetch) ----------
        if (tid < 96) {                 // Qux/Quu rows 32..47, all 48 cols
            float4 a0 = pf0, a1 = pf1;
            #pragma unroll 8
            for (int k = 0; k < NS; ++k) {
                float2 f2 = *(const float2*)&sF[k][i0b];
                float4 w4 = ld4(&sW[k][j0b]);
                fma4(a0, f2.x, w4); fma4(a1, f2.y, w4);
            }
            st4(&sQt[i0b][j0b], a0); st4(&sQt[i0b + 1][j0b], a1);
        } else if (tid < 224) {         // Qxx rows 0..31, cols 0..31
            float4 a0 = pf0, a1 = pf1;
            #pragma unroll 8
            for (int k = 0; k < NS; ++k) {
                float2 f2 = *(const float2*)&sF[k][i0x];
                float4 w4 = ld4(&sW[k][j0x]);
                fma4(a0, f2.x, w4); fma4(a1, f2.y, w4);
            }
            st4(&sQt[i0x][j0x], a0); st4(&sQt[i0x + 1][j0x], a1);
        } else {                        // qt = p + F^T z
            float a = pp0;
            #pragma unroll 8
            for (int k = 0; k < NS; ++k) a = fmaf(sF[k][ctq], sz[k], a);
            sqt[ctq] = a;
            if (ctq < 16) {
                float a2 = pp1;
                #pragma unroll 8
                for (int k = 0; k < NS; ++k) a2 = fmaf(sF[k][32 + ctq], sz[k], a2);
                sqt[32 + ctq] = a2;
            }
        }
        __syncthreads();

        // ---------------- Phase C: GJ (wave0) ; prefetch (tid>=64) ----------
        if (wv == 0) {
            float R[NC];
            if (lane < NC) {
                #pragma unroll
                for (int i = 0; i < NC; ++i) R[i] = sQt[NS + i][NS + lane];
            } else if (lane < NSC) {
                #pragma unroll
                for (int i = 0; i < NC; ++i) R[i] = sQt[NS + i][lane - NC];
            } else if (lane == NSC) {
                #pragma unroll
                for (int i = 0; i < NC; ++i) R[i] = sqt[NS + i];
            } else {
                #pragma unroll
                for (int i = 0; i < NC; ++i) R[i] = 0.f;
            }
            #pragma unroll
            for (int k = 0; k < NC; ++k) {
                float pk = rlane(R[k], k);
                float inv = __builtin_amdgcn_rcpf(pk);
                inv = inv * fmaf(-pk, inv, 2.0f);
                float tm = R[k] * inv;
                #pragma unroll
                for (int i = 0; i < NC; ++i) {
                    if (i == k) continue;
                    float cki = rlane(R[i], k);
                    R[i] = fmaf(-tm, cki, R[i]);
                }
                R[k] = tm;
            }
            if (lane >= NC && lane < NSC) {
                const int c = lane - NC;
                #pragma unroll
                for (int i = 0; i < NC; ++i) sKt[i][c] = -R[i];
            } else if (lane == NSC) {
                #pragma unroll
                for (int i = 0; i < NC; ++i) skt[i] = -R[i];
            }
        } else if (t > 0) {
            PREFETCH(t - 1);
        }
        __syncthreads();

        // ---------------- Phase D ----------------
        if (tid < 64) {
            if (t > 0) PREFETCH(t - 1);       // wave0's Qux fragments
        } else if (tid < 96) {                 // K,k -> workspace
            float4* Kg4 = (float4*)(Kws + ((size_t)b * T + t) * NC * NS);
            int e = (tid - 64) * 4;
            #pragma unroll
            for (int q = 0; q < 4; ++q)
                Kg4[e + q] = ld4(&sKt[(e + q) >> 3][((e + q) & 7) * 4]);
            if (tid < 68)
                ((float4*)(kws + ((size_t)b * T + t) * NC))[tid - 64] =
                    ld4(&skt[(tid - 64) * 4]);
        } else if (tid < 224) {                // V = Qxx + Qxu@K
            float4 a0 = ld4(&sQt[i0x][j0x]), a1 = ld4(&sQt[i0x + 1][j0x]);
            #pragma unroll
            for (int k = 0; k < NC; ++k) {
                float2 q2 = *(const float2*)&sQt[NS + k][i0x];  // Qxu = Qux^T
                float4 k4 = ld4(&sKt[k][j0x]);
                fma4(a0, q2.x, k4); fma4(a1, q2.y, k4);
            }
            st4(&sV[i0x][j0x], a0); st4(&sV[i0x + 1][j0x], a1);
        } else {                               // v = qx + Qxu@kt
            float a = sqt[ctq];
            #pragma unroll
            for (int k = 0; k < NC; ++k) a = fmaf(sQt[NS + k][ctq], skt[k], a);
            sv[ctq] = a;
        }
        __syncthreads();
    }
    #undef PREFETCH
}

// ================= forward chain kernel =================
// Single wave per block. lanes 48..63 ("u-lanes") hold K rows in registers
// with 2-step global lookahead; lanes 0..31 ("x-lanes") hold A,B rows.
// xu vector double-buffered in LDS; LDS-broadcast matvecs, no readlane.
__global__ __launch_bounds__(64)
void lqr_chain(const float* __restrict__ x_init,
               const float* __restrict__ A,
               const float* __restrict__ Bm,
               const float* __restrict__ c1,
               const float* __restrict__ Kws,
               const float* __restrict__ kws,
               float* __restrict__ out_x,
               float* __restrict__ out_u,
               float* __restrict__ out_cost)
{
    const int b = blockIdx.x;
    const int lane = threadIdx.x;

    __shared__ __align__(16) float sxu[2][64];

    if (lane == 0) out_cost[b] = 0.f;   // zeroed before cost kernel runs

    float4 Freg[12];
    float c1reg = 0.f, xv = 0.f;
    if (lane < 32) {
        const float* Ar = A + (size_t)b * NS * NS + lane * NS;
        const float* Br = Bm + (size_t)b * NS * NC + lane * NC;
        #pragma unroll
        for (int g = 0; g < 8; ++g) Freg[g] = ld4(Ar + g * 4);
        #pragma unroll
        for (int g = 0; g < 4; ++g) Freg[8 + g] = ld4(Br + g * 4);
        c1reg = c1[(size_t)b * NS + lane];
        xv = x_init[(size_t)b * NS + lane];
        sxu[0][lane] = xv;
    }

    const int r = lane - 48;
    const float* Kbase = Kws + (size_t)b * T * NC * NS;
    const float* kbase = kws + (size_t)b * T * NC;
    float4 KA[8], KB[8];
    float kA = 0.f, kB = 0.f;
    if (lane >= 48) {
        #pragma unroll
        for (int g = 0; g < 8; ++g) KA[g] = ld4(Kbase + r * NS + g * 4);
        kA = kbase[r];
        #pragma unroll
        for (int g = 0; g < 8; ++g) KB[g] = ld4(Kbase + NC * NS + r * NS + g * 4);
        kB = kbase[NC + r];
    }
    __syncthreads();

    for (int t = 0; t < T; t += 2) {
        // ---- even step: parity 0, use KA, reload KA with t+2 ----
        if (lane >= 48) {
            float u0 = kA, u1 = 0.f;
            #pragma unroll
            for (int g = 0; g < 8; g += 2) {
                u0 += dot4(KA[g],     ld4(&sxu[0][g * 4]));
                u1 += dot4(KA[g + 1], ld4(&sxu[0][g * 4 + 4]));
            }
            float u = u0 + u1;
            sxu[0][NS + r] = u;
            out_u[((size_t)b * T + t) * NC + r] = u;
            const int tl = (t + 2 < T) ? t + 2 : T - 1;
            const float* Kr = Kbase + (size_t)tl * NC * NS + r * NS;
            #pragma unroll
            for (int g = 0; g < 8; ++g) KA[g] = ld4(Kr + g * 4);
            kA = kbase[(size_t)tl * NC + r];
        }
        __syncthreads();
        if (lane < 32) {
            out_x[((size_t)b * T + t) * NS + lane] = xv;
            float a0 = c1reg, a1 = 0.f;
            #pragma unroll
            for (int g = 0; g < 12; g += 2) {
                a0 += dot4(Freg[g],     ld4(&sxu[0][g * 4]));
                a1 += dot4(Freg[g + 1], ld4(&sxu[0][g * 4 + 4]));
            }
            xv = a0 + a1;
            sxu[1][lane] = xv;
        }
        __syncthreads();

        // ---- odd step: parity 1, use KB, reload KB with t+3 ----
        if (lane >= 48) {
            float u0 = kB, u1 = 0.f;
            #pragma unroll
            for (int g = 0; g < 8; g += 2) {
                u0 += dot4(KB[g],     ld4(&sxu[1][g * 4]));
                u1 += dot4(KB[g + 1], ld4(&sxu[1][g * 4 + 4]));
            }
            float u = u0 + u1;
            sxu[1][NS + r] = u;
            out_u[((size_t)b * T + t + 1) * NC + r] = u;
            const int tl = (t + 3 < T) ? t + 3 : T - 1;
            const float* Kr = Kbase + (size_t)tl * NC * NS + r * NS;
            #pragma unroll
            for (int g = 0; g < 8; ++g) KB[g] = ld4(Kr + g * 4);
            kB = kbase[(size_t)tl * NC + r];
        }
        __syncthreads();
        if (lane < 32) {
            out_x[((size_t)b * T + t + 1) * NS + lane] = xv;
            float a0 = c1reg, a1 = 0.f;
            #pragma unroll
            for (int g = 0; g < 12; g += 2) {
                a0 += dot4(Freg[g],     ld4(&sxu[1][g * 4]));
                a1 += dot4(Freg[g + 1], ld4(&sxu[1][g * 4 + 4]));
            }
            xv = a0 + a1;
            sxu[0][lane] = xv;
        }
        __syncthreads();
    }
}

// ================= cost kernel =================
// 2 blocks per batch element (64 timesteps each), 4 blocks/CU.
// xu staged in LDS; Q read as a coalesced float4 stream; atomicAdd partials.
#define CT 64
__global__ __launch_bounds__(256, 4)
void lqr_cost(const float* __restrict__ Q,
              const float* __restrict__ p,
              const float* __restrict__ out_x,
              const float* __restrict__ out_u,
              float* __restrict__ out_cost)
{
    const int blk = blockIdx.x;
    const int b = blk >> 1;
    const int t0 = (blk & 1) * CT;
    const int tid = threadIdx.x;

    __shared__ __align__(16) float sxu[CT][NSC];   // 12 KB
    __shared__ float sred[4];

    const float4* gx = (const float4*)(out_x + ((size_t)b * T + t0) * NS);
    const float4* gu = (const float4*)(out_u + ((size_t)b * T + t0) * NC);
    for (int q = tid; q < CT * 8; q += 256) st4(&sxu[q >> 3][(q & 7) * 4], gx[q]);
    for (int q = tid; q < CT * 4; q += 256) st4(&sxu[q >> 2][NS + (q & 3) * 4], gu[q]);
    __syncthreads();

    float acc = 0.f;
    const float4* Qf4 = (const float4*)(Q + ((size_t)b * T + t0) * NSC * NSC);
    for (int q = tid; q < CT * 576; q += 256) {
        int t = q / 576, rem = q - t * 576;
        int i = rem / 12, jg = rem - i * 12;
        float4 qv = Qf4[q];
        acc = fmaf(0.5f * sxu[t][i], dot4(qv, ld4(&sxu[t][jg * 4])), acc);
    }
    const float* pg = p + ((size_t)b * T + t0) * NSC;
    for (int e = tid; e < CT * NSC; e += 256) {
        int t = e / NSC, j = e - t * NSC;
        acc = fmaf(pg[e], sxu[t][j], acc);
    }

    for (int off = 32; off > 0; off >>= 1)
        acc += __shfl_down(acc, off, 64);
    if ((tid & 63) == 0) sred[tid >> 6] = acc;
    __syncthreads();
    if (tid == 0)
        atomicAdd(out_cost + b, (sred[0] + sred[1]) + (sred[2] + sred[3]));
}

extern "C" void kernel_launch(void* const* d_in, const int* in_sizes, int n_in,
                              void* d_out, int out_size, void* d_ws, size_t ws_size,
                              hipStream_t stream) {
    const float* x_init = (const float*)d_in[0];
    const float* Q      = (const float*)d_in[1];
    const float* p      = (const float*)d_in[2];
    const float* A      = (const float*)d_in[3];
    const float* Bm     = (const float*)d_in[4];
    const float* c1     = (const float*)d_in[5];

    float* out      = (float*)d_out;
    float* out_x    = out;
    float* out_u    = out + (size_t)NB * T * NS;
    float* out_cost = out + (size_t)NB * T * (NS + NC);

    float* Kws = (float*)d_ws;
    float* kws = Kws + (size_t)NB * T * NC * NS;

    lqr_backward<<<NB, 256, 0, stream>>>(Q, p, A, Bm, c1, Kws, kws);
    lqr_chain<<<NB, 64, 0, stream>>>(x_init, A, Bm, c1, Kws, kws,
                                     out_x, out_u, out_cost);
    lqr_cost<<<NB * 2, 256, 0, stream>>>(Q, p, out_x, out_u, out_cost);
}